// Round 2
// baseline (271.113 us; speedup 1.0000x reference)
//
#include <hip/hip_runtime.h>

// Problem constants (from reference)
#define NUM_TOKENS   16384
#define NUM_HEADS    8
#define HEAD_SIZE    128
#define NUM_BLOCKS   4096
#define BLOCK_SIZE_  16
#define SLOT_ELEMS   (NUM_HEADS * HEAD_SIZE)          // 1024 floats per slot
#define NUM_SLOTS    (NUM_BLOCKS * BLOCK_SIZE_)       // 65536
#define CACHE_ELEMS  ((long)NUM_SLOTS * SLOT_ELEMS)   // 67,108,864 floats per cache

// Pass 1: copy both input caches to the output buffer (vectorized float4,
// grid-stride).
__global__ void copy_cache_kernel(const float4* __restrict__ kc,
                                  const float4* __restrict__ vc,
                                  float4* __restrict__ ok,
                                  float4* __restrict__ ov,
                                  long n4) {
    long i = (long)blockIdx.x * blockDim.x + threadIdx.x;
    long stride = (long)gridDim.x * blockDim.x;
    for (; i < n4; i += stride) {
        ok[i] = kc[i];
        ov[i] = vc[i];
    }
}

// Pass 2: scatter tokens. One block (256 threads) per token; each thread
// moves one float4 (16 B) of key and one of value. Each token's slot data is
// 1024 floats = 256 float4 — exactly one block's worth. Writes per token are
// a contiguous 4 KB run in each cache: fully coalesced.
__global__ void scatter_kv_kernel(const float4* __restrict__ key,
                                  const float4* __restrict__ value,
                                  const int* __restrict__ slot_mapping,
                                  float4* __restrict__ ok,
                                  float4* __restrict__ ov) {
    int token = blockIdx.x;
    int slot = slot_mapping[token];   // harness pushes integer inputs as int32
    if (slot < 0) return;             // dropped token
    int tid = threadIdx.x;            // 0..255
    long src = (long)token * (SLOT_ELEMS / 4) + tid;
    long dst = (long)slot  * (SLOT_ELEMS / 4) + tid;
    ok[dst] = key[src];
    ov[dst] = value[src];
}

extern "C" void kernel_launch(void* const* d_in, const int* in_sizes, int n_in,
                              void* d_out, int out_size, void* d_ws, size_t ws_size,
                              hipStream_t stream) {
    const float* key   = (const float*)d_in[0];
    const float* value = (const float*)d_in[1];
    const float* kc    = (const float*)d_in[2];
    const float* vc    = (const float*)d_in[3];
    const int*   slots = (const int*)d_in[4];   // int32 on device (harness contract)
    // d_in[5], d_in[6] = k_scale, v_scale — unused (kv_cache_dtype='auto')

    float* ok = (float*)d_out;
    float* ov = ok + CACHE_ELEMS;

    long n4 = CACHE_ELEMS / 4;  // 16,777,216 float4 per cache

    // 2048 blocks x 256 threads: 524,288 lanes, 32 grid-stride iters each.
    copy_cache_kernel<<<2048, 256, 0, stream>>>(
        (const float4*)kc, (const float4*)vc, (float4*)ok, (float4*)ov, n4);

    // One block per token; scatter must run after the copy (same stream).
    scatter_kv_kernel<<<NUM_TOKENS, 256, 0, stream>>>(
        (const float4*)key, (const float4*)value, slots, (float4*)ok, (float4*)ov);
}

// Round 3
// 203.348 us; speedup vs baseline: 1.3332x; 1.3332x over previous
//
#include <hip/hip_runtime.h>

// Problem constants (from reference)
#define NUM_TOKENS   16384
#define NUM_HEADS    8
#define HEAD_SIZE    128
#define NUM_BLOCKS   4096
#define BLOCK_SIZE_  16
#define SLOT_ELEMS   (NUM_HEADS * HEAD_SIZE)          // 1024 floats per slot
#define SLOT_VEC4    (SLOT_ELEMS / 4)                 // 256 float4 per slot
#define NUM_SLOTS    (NUM_BLOCKS * BLOCK_SIZE_)       // 65536
#define CACHE_ELEMS  ((long)NUM_SLOTS * SLOT_ELEMS)   // 67,108,864 floats per cache

// --- Fused path -------------------------------------------------------------

// inv[slot] = token index writing that slot, or -1. Slots are unique, so the
// scatter is race-free. (inv is pre-filled with -1 via hipMemsetAsync 0xFF.)
__global__ void build_inverse_kernel(const int* __restrict__ slot_mapping,
                                     int* __restrict__ inv) {
    int t = blockIdx.x * blockDim.x + threadIdx.x;
    if (t < NUM_TOKENS) {
        int s = slot_mapping[t];
        if (s >= 0) inv[s] = t;
    }
}

// One 256-thread block per slot. Each thread moves one float4 of K and one of
// V. Source is either the new token (if this slot is overwritten) or the old
// cache — wave-uniform branch. Output written exactly once: minimal traffic.
__global__ void fused_cache_kernel(const float4* __restrict__ key,
                                   const float4* __restrict__ value,
                                   const float4* __restrict__ kc,
                                   const float4* __restrict__ vc,
                                   const int* __restrict__ inv,
                                   float4* __restrict__ ok,
                                   float4* __restrict__ ov) {
    int slot = blockIdx.x;
    int tid  = threadIdx.x;                    // 0..255
    int token = inv[slot];
    long dst = (long)slot * SLOT_VEC4 + tid;
    if (token >= 0) {
        long src = (long)token * SLOT_VEC4 + tid;
        ok[dst] = key[src];
        ov[dst] = value[src];
    } else {
        ok[dst] = kc[dst];
        ov[dst] = vc[dst];
    }
}

// --- Fallback two-pass path (if ws too small) -------------------------------

__global__ void copy_cache_kernel(const float4* __restrict__ kc,
                                  const float4* __restrict__ vc,
                                  float4* __restrict__ ok,
                                  float4* __restrict__ ov,
                                  long n4) {
    long i = (long)blockIdx.x * blockDim.x + threadIdx.x;
    long stride = (long)gridDim.x * blockDim.x;
    for (; i < n4; i += stride) {
        ok[i] = kc[i];
        ov[i] = vc[i];
    }
}

__global__ void scatter_kv_kernel(const float4* __restrict__ key,
                                  const float4* __restrict__ value,
                                  const int* __restrict__ slot_mapping,
                                  float4* __restrict__ ok,
                                  float4* __restrict__ ov) {
    int token = blockIdx.x;
    int slot = slot_mapping[token];
    if (slot < 0) return;
    int tid = threadIdx.x;
    long src = (long)token * SLOT_VEC4 + tid;
    long dst = (long)slot  * SLOT_VEC4 + tid;
    ok[dst] = key[src];
    ov[dst] = value[src];
}

extern "C" void kernel_launch(void* const* d_in, const int* in_sizes, int n_in,
                              void* d_out, int out_size, void* d_ws, size_t ws_size,
                              hipStream_t stream) {
    const float* key   = (const float*)d_in[0];
    const float* value = (const float*)d_in[1];
    const float* kc    = (const float*)d_in[2];
    const float* vc    = (const float*)d_in[3];
    const int*   slots = (const int*)d_in[4];   // int32 on device (harness contract)
    // d_in[5], d_in[6] = k_scale, v_scale — unused (kv_cache_dtype='auto')

    float* ok = (float*)d_out;
    float* ov = ok + CACHE_ELEMS;

    if (ws_size >= (size_t)NUM_SLOTS * sizeof(int)) {
        int* inv = (int*)d_ws;
        // Fill inv with -1 (0xFF bytes). hipMemsetAsync is graph-capture safe.
        hipMemsetAsync(inv, 0xFF, NUM_SLOTS * sizeof(int), stream);
        build_inverse_kernel<<<(NUM_TOKENS + 255) / 256, 256, 0, stream>>>(slots, inv);
        fused_cache_kernel<<<NUM_SLOTS, 256, 0, stream>>>(
            (const float4*)key, (const float4*)value,
            (const float4*)kc, (const float4*)vc, inv,
            (float4*)ok, (float4*)ov);
    } else {
        long n4 = CACHE_ELEMS / 4;
        copy_cache_kernel<<<2048, 256, 0, stream>>>(
            (const float4*)kc, (const float4*)vc, (float4*)ok, (float4*)ov, n4);
        scatter_kv_kernel<<<NUM_TOKENS, 256, 0, stream>>>(
            (const float4*)key, (const float4*)value, slots, (float4*)ok, (float4*)ov);
    }
}